// Round 5
// baseline (367.888 us; speedup 1.0000x reference)
//
#include <hip/hip_runtime.h>
#include <hip/hip_bf16.h>
#include <math.h>

// ---------------- problem constants ----------------
#define NB 32
#define QL 32
#define DL 1024
#define EMB 300
#define EMBP 320            // padded K-dim per tap (zeros 300..319)
#define OD 128
#define KNUM 21
#define VOCAB 50000

typedef short short8 __attribute__((ext_vector_type(8)));
typedef float floatx4 __attribute__((ext_vector_type(4)));

// workspace layout (in float units)
static const size_t WP_OFF = 0;                        // packed bf16 weights (122880 f)
static const size_t DPK_OFF = 122880;                  // packed doc bf16 [32*1024][320] = 5242880 f
static const size_t QPK_OFF = 5365760;                 // packed query bf16 [32*32][320] = 163840 f
static const size_t QENC_OFF = 8122880;
static const size_t QENC_SZ = NB * QL * OD;            // 131072
static const size_t DENC_OFF = QENC_OFF + 3 * QENC_SZ;
static const size_t DENC_SZ = (size_t)NB * DL * OD;    // 4194304
static const size_t ACC_OFF = DENC_OFF + 3 * DENC_SZ;
static const int ACC_SZ = 9 * NB * QL * KNUM;          // 193536

__device__ __constant__ int WPOFF_C[3] = {0, 40960, 122880};

// ---------------- weights -> bf16, layout [o][j*320+c] ----------------
__global__ void prep_w_kernel(const float* __restrict__ w1,
                              const float* __restrict__ w2,
                              const float* __restrict__ w3,
                              ushort* __restrict__ wp) {
    int idx = blockIdx.x * 256 + threadIdx.x;
    if (idx >= 245760) return;
    const float* src;
    int k, rel, base;
    if (idx < 40960)        { k = 1; rel = idx;          src = w1; base = 0; }
    else if (idx < 122880)  { k = 2; rel = idx - 40960;  src = w2; base = 40960; }
    else                    { k = 3; rel = idx - 122880; src = w3; base = 122880; }
    int kd = 320 * k;
    int o = rel / kd;
    int jc = rel - o * kd;
    int j = jc / EMBP;
    int c = jc - j * EMBP;
    float f = (c < EMB) ? src[(o * EMB + c) * k + j] : 0.f;
    __hip_bfloat16 h = __float2bfloat16(f);
    wp[base + rel] = *reinterpret_cast<ushort*>(&h);
}

// ---------------- gather token rows: fp32 emb -> packed bf16 [row][320] ----------------
__global__ void gather_pack(const float* __restrict__ emb, const int* __restrict__ ids,
                            int n_rows, ushort* __restrict__ dst) {
    int idx = blockIdx.x * 256 + threadIdx.x;    // one uint4 (8 bf16) per thread
    if (idx >= n_rows * 40) return;
    int r = idx / 40;
    int c0 = (idx - r * 40) * 8;
    int rid = ids[r];
    const float* erow = emb + (size_t)rid * EMB;
    ushort v[8];
    if (c0 + 8 <= EMB) {
        float4 f0 = *reinterpret_cast<const float4*>(erow + c0);
        float4 f1 = *reinterpret_cast<const float4*>(erow + c0 + 4);
        float fv[8] = {f0.x, f0.y, f0.z, f0.w, f1.x, f1.y, f1.z, f1.w};
#pragma unroll
        for (int i = 0; i < 8; ++i) {
            __hip_bfloat16 h = __float2bfloat16(fv[i]);
            v[i] = *reinterpret_cast<ushort*>(&h);
        }
    } else {
#pragma unroll
        for (int i = 0; i < 8; ++i) {
            int c = c0 + i;
            float f = (c < EMB) ? erow[c] : 0.f;
            __hip_bfloat16 h = __float2bfloat16(f);
            v[i] = *reinterpret_cast<ushort*>(&h);
        }
    }
    *reinterpret_cast<uint4*>(dst + (size_t)r * EMBP + c0) = *reinterpret_cast<uint4*>(v);
}

// ---------------- conv via bf16 MFMA, fragments direct from global (no LDS staging) ----------------
// grid: (mtiles, NB, 3). Block 256 = 4 waves, tile M=128 (l) x N=128 (o).
__global__ __launch_bounds__(256) void conv_mfma(const ushort* __restrict__ xs,
                                                 const float* __restrict__ mask,
                                                 int L, size_t enc_sz,
                                                 const ushort* __restrict__ wp,
                                                 const float* __restrict__ b1,
                                                 const float* __restrict__ b2,
                                                 const float* __restrict__ b3,
                                                 float* __restrict__ enc) {
    __shared__ float rowsum[2][128];

    const int tid = threadIdx.x;
    const int b = blockIdx.y;
    const int z = blockIdx.z;
    const int Kdim = EMBP * (z + 1);
    const int NCH = Kdim >> 6;
    const int l0 = blockIdx.x * 128;
    const int Lk = L - z;
    const ushort* wpk = wp + WPOFF_C[z];
    const ushort* xb = xs + (size_t)b * L * EMBP;
    const float* bias = (z == 0) ? b1 : ((z == 1) ? b2 : b3);
    float* out = enc + (size_t)z * enc_sz;

    const int wave = tid >> 6;
    const int lane = tid & 63;
    const int wm = wave >> 1;
    const int wn = wave & 1;
    const int l15 = lane & 15;
    const int quad = lane >> 4;

    floatx4 acc[4][4];
#pragma unroll
    for (int i = 0; i < 4; ++i)
#pragma unroll
        for (int j = 0; j < 4; ++j) acc[i][j] = (floatx4)0.f;

    // precompute clamped A-row pointers (rows fixed across chunks except tap offset jj)
    for (int ch = 0; ch < NCH; ++ch) {
        const int k0 = ch << 6;
        const int jj = ch / 5;                 // tap index (chunks of 64, 5 per tap)
        const int c0 = (ch - jj * 5) << 6;     // col within row
#pragma unroll
        for (int h = 0; h < 2; ++h) {
            short8 af[4], bf[4];
#pragma unroll
            for (int i = 0; i < 4; ++i) {
                int row = l0 + wm * 64 + i * 16 + l15 + jj;
                if (row > L - 1) row = L - 1;
                af[i] = *reinterpret_cast<const short8*>(xb + (size_t)row * EMBP + c0 + h * 32 + (quad << 3));
                int n = wn * 64 + i * 16 + l15;
                bf[i] = *reinterpret_cast<const short8*>(wpk + (size_t)n * Kdim + k0 + h * 32 + (quad << 3));
            }
#pragma unroll
            for (int i = 0; i < 4; ++i)
#pragma unroll
                for (int j = 0; j < 4; ++j)
                    acc[i][j] = __builtin_amdgcn_mfma_f32_16x16x32_bf16(af[i], bf[j], acc[i][j], 0, 0, 0);
        }
    }

    // epilogue: bias + relu, row sum-of-squares, normalize + mask
    float bv[4];
#pragma unroll
    for (int j = 0; j < 4; ++j) bv[j] = bias[wn * 64 + j * 16 + l15];
#pragma unroll
    for (int i = 0; i < 4; ++i)
#pragma unroll
        for (int r = 0; r < 4; ++r) {
            float p = 0.f;
#pragma unroll
            for (int j = 0; j < 4; ++j) {
                float y = fmaxf(acc[i][j][r] + bv[j], 0.f);
                acc[i][j][r] = y;
                p += y * y;
            }
#pragma unroll
            for (int m = 1; m < 16; m <<= 1) p += __shfl_xor(p, m, 64);
            if (l15 == 0) rowsum[wn][wm * 64 + i * 16 + quad * 4 + r] = p;
        }
    __syncthreads();

#pragma unroll
    for (int i = 0; i < 4; ++i) {
        int mbase = wm * 64 + i * 16 + quad * 4;
#pragma unroll
        for (int r = 0; r < 4; ++r) {
            int row = mbase + r;
            int l = l0 + row;
            if (l < Lk) {
                float tot = rowsum[0][row] + rowsum[1][row];
                float mv = mask[b * L + l];
                float sc = mv / (sqrtf(tot) + 1e-13f);
                float* op = out + ((size_t)(b * L + l)) * OD + wn * 64 + l15;
#pragma unroll
                for (int j = 0; j < 4; ++j)
                    op[j * 16] = acc[i][j][r] * sc;
            }
        }
    }
}

// ---------------- matcher: dot tile + geometric-chain gaussian histogram ----------------
// grid: (vtile=8, b=32, pair=9), block 256.
__global__ __launch_bounds__(256, 4) void matcher_kernel(const float* __restrict__ qenc,
                                                         const float* __restrict__ denc,
                                                         float* __restrict__ accb) {
    __shared__ __align__(16) float lds[5440];
    float* Qs = lds;                   // [32 k][36 q]
    float* Vs = lds + 1152;            // [32 k][132 v]
    // after dots: Sm = [32 q][32 float4 cols], XOR-swizzled: phys col = logical ^ q

    const int tid = threadIdx.x;
    const int pp = blockIdx.z;
    const int b = blockIdx.y;
    const int v0 = blockIdx.x * 128;
    const int qi = pp / 3;
    const int di = pp - qi * 3;
    const int Vk = 1024 - di;
    const float* qptr = qenc + qi * QENC_SZ + (size_t)b * (QL * OD);
    const float* vptr = denc + di * DENC_SZ + (size_t)b * (DL * OD);

    const int vg32 = tid & 31;
    const int qg = tid >> 5;
    const int vt = vg32 * 4;
    const int qt = qg * 4;
    float acc[4][4];
#pragma unroll
    for (int i = 0; i < 4; ++i)
#pragma unroll
        for (int j = 0; j < 4; ++j) acc[i][j] = 0.f;

    const int ks = tid & 31;
    const int rb = tid >> 5;           // 0..7

    for (int ch = 0; ch < 4; ++ch) {
        const int k0 = ch * 32;
#pragma unroll
        for (int pass = 0; pass < 4; ++pass) {
            int q = rb + pass * 8;
            Qs[ks * 36 + q] = qptr[q * OD + k0 + ks];
        }
#pragma unroll
        for (int pass = 0; pass < 16; ++pass) {
            int v = rb + pass * 8;
            Vs[ks * 132 + v] = vptr[(size_t)(v0 + v) * OD + k0 + ks];
        }
        __syncthreads();
#pragma unroll 8
        for (int k = 0; k < 32; ++k) {
            float4 qv = *reinterpret_cast<const float4*>(&Qs[k * 36 + qt]);
            float4 vv = *reinterpret_cast<const float4*>(&Vs[k * 132 + vt]);
            float qa[4] = {qv.x, qv.y, qv.z, qv.w};
            float va[4] = {vv.x, vv.y, vv.z, vv.w};
#pragma unroll
            for (int i = 0; i < 4; ++i)
#pragma unroll
                for (int j = 0; j < 4; ++j) acc[i][j] += qa[i] * va[j];
        }
        __syncthreads();
    }
    // store S tile, XOR-swizzled (phys float4 col = vg32 ^ q), stride 32 float4
    float4* Sm4 = reinterpret_cast<float4*>(lds);
#pragma unroll
    for (int i = 0; i < 4; ++i) {
        int q = qt + i;
        int pc = vg32 ^ q;
        Sm4[q * 32 + pc] = make_float4(acc[i][0], acc[i][1], acc[i][2], acc[i][3]);
    }
    __syncthreads();

    // gaussian phase: thread = (q, 16-v strip vs). Geometric chain: 3 exps per sim.
    const int q = tid >> 3;
    const int vs = tid & 7;
    const int vmax = min(128, Vk - v0);      // block-uniform
    const int elim = vmax - vs * 16;         // valid elements in this strip (<=16)

    float sa[16];
#pragma unroll
    for (int g2 = 0; g2 < 4; ++g2) {
        int pc = (vs * 4 + g2) ^ q;
        float4 s4 = Sm4[q * 32 + pc];
        sa[g2 * 4 + 0] = s4.x; sa[g2 * 4 + 1] = s4.y;
        sa[g2 * 4 + 2] = s4.z; sa[g2 * 4 + 3] = s4.w;
    }

    float kacc[KNUM];
#pragma unroll
    for (int t = 0; t < KNUM; ++t) kacc[t] = 0.f;

#pragma unroll
    for (int v = 0; v < 16; ++v) {
        if (v < elim) {
            float s = sa[v];
            float d0 = s - 1.0f;
            kacc[0] += __builtin_exp2f(-721347.52f * d0 * d0);       // sigma=0.001
            float d1 = s - 0.95f;
            float e = __builtin_exp2f(-72.13475204f * d1 * d1);      // kernel t=1
            float r = __builtin_exp2f(fmaf(-14.426950408f, d1, -0.7213475204f));
#pragma unroll
            for (int t = 1; t < KNUM; ++t) {
                kacc[t] += e;
                e *= r;
                r *= 0.36787944117f;                                  // e^-1
            }
        }
    }
    // reduce across the 8 v-strips sharing q (lanes differ only in low 3 bits)
#pragma unroll
    for (int t = 0; t < KNUM; ++t) {
        float v = kacc[t];
        v += __shfl_xor(v, 1, 64);
        v += __shfl_xor(v, 2, 64);
        v += __shfl_xor(v, 4, 64);
        kacc[t] = v;
    }
    if (vs == 0) {
        float* dst = &accb[((pp * NB + b) * QL + q) * KNUM];
#pragma unroll
        for (int t = 0; t < KNUM; ++t) atomicAdd(&dst[t], kacc[t]);
    }
}

// ---------------- finalize ----------------
__global__ void finalize_kernel(const float* __restrict__ accb,
                                const float* __restrict__ qmask,
                                const float* __restrict__ dw,
                                const float* __restrict__ db,
                                float* __restrict__ out) {
    __shared__ float prod[192];
    int b = blockIdx.x;
    int tid = threadIdx.x;
    if (tid < 189) {
        int pq = tid / 21;
        int t = tid - pq * 21;
        int qi = pq / 3;
        int Qk = 32 - qi;
        const float* ab = accb + ((pq * NB + b) * QL) * KNUM + t;
        float s = 0.f;
        for (int q = 0; q < Qk; ++q)
            s += logf(fmaxf(ab[q * KNUM], 1e-10f)) * qmask[b * QL + q];
        float lg = s * 0.01f;
        out[NB + b * 189 + tid] = lg;
        prod[tid] = lg * dw[tid];
    }
    __syncthreads();
    if (tid == 0) {
        float sc = db[0];
        for (int i = 0; i < 189; ++i) sc += prod[i];
        out[b] = sc;
    }
}

// ---------------- launcher ----------------
extern "C" void kernel_launch(void* const* d_in, const int* in_sizes, int n_in,
                              void* d_out, int out_size, void* d_ws, size_t ws_size,
                              hipStream_t stream) {
    const int* qids = (const int*)d_in[0];
    const float* qmask = (const float*)d_in[1];
    const int* dids = (const int*)d_in[2];
    const float* dmask = (const float*)d_in[3];
    const float* emb = (const float*)d_in[4];
    const float* w1 = (const float*)d_in[5];
    const float* b1 = (const float*)d_in[6];
    const float* w2 = (const float*)d_in[7];
    const float* b2 = (const float*)d_in[8];
    const float* w3 = (const float*)d_in[9];
    const float* b3 = (const float*)d_in[10];
    const float* dw = (const float*)d_in[11];
    const float* db = (const float*)d_in[12];
    float* out = (float*)d_out;
    float* ws = (float*)d_ws;

    ushort* wp = (ushort*)(ws + WP_OFF);
    ushort* dpk = (ushort*)(ws + DPK_OFF);
    ushort* qpk = (ushort*)(ws + QPK_OFF);
    float* qenc = ws + QENC_OFF;
    float* denc = ws + DENC_OFF;
    float* accb = ws + ACC_OFF;

    hipMemsetAsync(accb, 0, ACC_SZ * sizeof(float), stream);
    prep_w_kernel<<<960, 256, 0, stream>>>(w1, w2, w3, wp);
    gather_pack<<<(NB * DL * 40 + 255) / 256, 256, 0, stream>>>(emb, dids, NB * DL, dpk);
    gather_pack<<<(NB * QL * 40 + 255) / 256, 256, 0, stream>>>(emb, qids, NB * QL, qpk);

    conv_mfma<<<dim3(8, NB, 3), 256, 0, stream>>>(dpk, dmask, DL, DENC_SZ, wp, b1, b2, b3, denc);
    conv_mfma<<<dim3(1, NB, 3), 256, 0, stream>>>(qpk, qmask, QL, QENC_SZ, wp, b1, b2, b3, qenc);

    matcher_kernel<<<dim3(8, NB, 9), 256, 0, stream>>>(qenc, denc, accb);
    finalize_kernel<<<NB, 256, 0, stream>>>(accb, qmask, dw, db, out);
}

// Round 6
// 348.688 us; speedup vs baseline: 1.0551x; 1.0551x over previous
//
#include <hip/hip_runtime.h>
#include <hip/hip_bf16.h>
#include <math.h>

// ---------------- problem constants ----------------
#define NB 32
#define QL 32
#define DL 1024
#define EMB 300
#define EMBP 320            // padded K-dim per tap (zeros 300..319)
#define OD 128
#define KNUM 21
#define VOCAB 50000

typedef short short8 __attribute__((ext_vector_type(8)));
typedef float floatx4 __attribute__((ext_vector_type(4)));

// workspace layout (in float units)
static const size_t WP_OFF = 0;                        // packed bf16 weights (122880 f)
static const size_t DPK_OFF = 122880;                  // packed doc bf16 [32*1024][320]
static const size_t QPK_OFF = 5365760;                 // packed query bf16 [32*32][320]
static const size_t QENC_OFF = 8122880;
static const size_t QENC_SZ = NB * QL * OD;            // 131072
static const size_t DENC_OFF = QENC_OFF + 3 * QENC_SZ;
static const size_t DENC_SZ = (size_t)NB * DL * OD;    // 4194304
static const size_t ACC_OFF = DENC_OFF + 3 * DENC_SZ;
static const int ACC_SZ = 9 * NB * QL * KNUM;          // 193536

__device__ __constant__ int WPOFF_C[3] = {0, 40960, 122880};

// ---------------- weights -> bf16, layout [o][j*320+c] ----------------
__global__ void prep_w_kernel(const float* __restrict__ w1,
                              const float* __restrict__ w2,
                              const float* __restrict__ w3,
                              ushort* __restrict__ wp) {
    int idx = blockIdx.x * 256 + threadIdx.x;
    if (idx >= 245760) return;
    const float* src;
    int k, rel, base;
    if (idx < 40960)        { k = 1; rel = idx;          src = w1; base = 0; }
    else if (idx < 122880)  { k = 2; rel = idx - 40960;  src = w2; base = 40960; }
    else                    { k = 3; rel = idx - 122880; src = w3; base = 122880; }
    int kd = 320 * k;
    int o = rel / kd;
    int jc = rel - o * kd;
    int j = jc / EMBP;
    int c = jc - j * EMBP;
    float f = (c < EMB) ? src[(o * EMB + c) * k + j] : 0.f;
    __hip_bfloat16 h = __float2bfloat16(f);
    wp[base + rel] = *reinterpret_cast<ushort*>(&h);
}

// ---------------- gather token rows: fp32 emb -> packed bf16 [row][320] (doc + query in one) ----------------
__global__ void gather_pack(const float* __restrict__ emb,
                            const int* __restrict__ dids, const int* __restrict__ qids,
                            ushort* __restrict__ dpk, ushort* __restrict__ qpk) {
    int idx = blockIdx.x * 256 + threadIdx.x;    // one uint4 (8 bf16) per thread
    const int DROWS = NB * DL;
    if (idx >= (DROWS + NB * QL) * 40) return;
    int r = idx / 40;
    int c0 = (idx - r * 40) * 8;
    int rid;
    ushort* dst;
    if (r < DROWS) { rid = dids[r]; dst = dpk + (size_t)r * EMBP; }
    else           { rid = qids[r - DROWS]; dst = qpk + (size_t)(r - DROWS) * EMBP; }
    const float* erow = emb + (size_t)rid * EMB;
    ushort v[8];
    if (c0 + 8 <= EMB) {
        float4 f0 = *reinterpret_cast<const float4*>(erow + c0);
        float4 f1 = *reinterpret_cast<const float4*>(erow + c0 + 4);
        float fv[8] = {f0.x, f0.y, f0.z, f0.w, f1.x, f1.y, f1.z, f1.w};
#pragma unroll
        for (int i = 0; i < 8; ++i) {
            __hip_bfloat16 h = __float2bfloat16(fv[i]);
            v[i] = *reinterpret_cast<ushort*>(&h);
        }
    } else {
#pragma unroll
        for (int i = 0; i < 8; ++i) {
            int c = c0 + i;
            float f = (c < EMB) ? erow[c] : 0.f;
            __hip_bfloat16 h = __float2bfloat16(f);
            v[i] = *reinterpret_cast<ushort*>(&h);
        }
    }
    *reinterpret_cast<uint4*>(dst + c0) = *reinterpret_cast<uint4*>(v);
}

// ---------------- conv via bf16 MFMA, register ping-pong prefetch, doc+query in one grid ----------------
// grid: (9, NB, 3). x<8: doc tiles (M=128 l), x==8: query tile. Block 256 = 4 waves, 128x128.
__global__ __launch_bounds__(256) void conv_mfma(const ushort* __restrict__ dpk,
                                                 const ushort* __restrict__ qpk,
                                                 const float* __restrict__ dmask,
                                                 const float* __restrict__ qmask,
                                                 const ushort* __restrict__ wp,
                                                 const float* __restrict__ b1,
                                                 const float* __restrict__ b2,
                                                 const float* __restrict__ b3,
                                                 float* __restrict__ denc,
                                                 float* __restrict__ qenc) {
    __shared__ float rowsum[2][128];

    const int tid = threadIdx.x;
    const int b = blockIdx.y;
    const int z = blockIdx.z;
    const bool isq = (blockIdx.x == 8);
    const ushort* xs = isq ? qpk : dpk;
    const float* mask = isq ? qmask : dmask;
    const int L = isq ? QL : DL;
    const size_t enc_sz = isq ? QENC_SZ : DENC_SZ;
    const int l0 = isq ? 0 : blockIdx.x * 128;
    const int Kdim = EMBP * (z + 1);
    const int NH = 10 * (z + 1);          // half-chunks of 32 shorts
    const int Lk = L - z;
    const ushort* wpk = wp + WPOFF_C[z];
    const ushort* xb = xs + (size_t)b * L * EMBP;
    const float* bias = (z == 0) ? b1 : ((z == 1) ? b2 : b3);
    float* out = (isq ? qenc : denc) + (size_t)z * enc_sz;

    const int wave = tid >> 6;
    const int lane = tid & 63;
    const int wm = wave >> 1;
    const int wn = wave & 1;
    const int l15 = lane & 15;
    const int quad = lane >> 4;

    floatx4 acc[4][4];
#pragma unroll
    for (int i = 0; i < 4; ++i)
#pragma unroll
        for (int j = 0; j < 4; ++j) acc[i][j] = (floatx4)0.f;

    auto load_frags = [&](int hh, short8* A, short8* B) {
        int ch = hh >> 1;
        int h = hh & 1;
        int jj = ch / 5;                          // conv tap
        int c0 = (ch - jj * 5) << 6;              // col within row
        int aoff = c0 + h * 32 + (quad << 3);
        int boff = (ch << 6) + h * 32 + (quad << 3);
#pragma unroll
        for (int i = 0; i < 4; ++i) {
            int row = l0 + wm * 64 + i * 16 + l15 + jj;
            if (row > L - 1) row = L - 1;
            A[i] = *reinterpret_cast<const short8*>(xb + (size_t)row * EMBP + aoff);
            int n = wn * 64 + i * 16 + l15;
            B[i] = *reinterpret_cast<const short8*>(wpk + (size_t)n * Kdim + boff);
        }
    };

    short8 afA[4], bfA[4], afB[4], bfB[4];
    load_frags(0, afA, bfA);
    for (int hh = 0; hh < NH; hh += 2) {
        load_frags(hh + 1, afB, bfB);
#pragma unroll
        for (int i = 0; i < 4; ++i)
#pragma unroll
            for (int j = 0; j < 4; ++j)
                acc[i][j] = __builtin_amdgcn_mfma_f32_16x16x32_bf16(afA[i], bfA[j], acc[i][j], 0, 0, 0);
        int nx = (hh + 2 < NH) ? hh + 2 : NH - 1;
        load_frags(nx, afA, bfA);
#pragma unroll
        for (int i = 0; i < 4; ++i)
#pragma unroll
            for (int j = 0; j < 4; ++j)
                acc[i][j] = __builtin_amdgcn_mfma_f32_16x16x32_bf16(afB[i], bfB[j], acc[i][j], 0, 0, 0);
    }

    // epilogue: bias + relu, row sum-of-squares, normalize + mask
    float bv[4];
#pragma unroll
    for (int j = 0; j < 4; ++j) bv[j] = bias[wn * 64 + j * 16 + l15];
#pragma unroll
    for (int i = 0; i < 4; ++i)
#pragma unroll
        for (int r = 0; r < 4; ++r) {
            float p = 0.f;
#pragma unroll
            for (int j = 0; j < 4; ++j) {
                float y = fmaxf(acc[i][j][r] + bv[j], 0.f);
                acc[i][j][r] = y;
                p += y * y;
            }
#pragma unroll
            for (int m = 1; m < 16; m <<= 1) p += __shfl_xor(p, m, 64);
            if (l15 == 0) rowsum[wn][wm * 64 + i * 16 + quad * 4 + r] = p;
        }
    __syncthreads();

#pragma unroll
    for (int i = 0; i < 4; ++i) {
        int mbase = wm * 64 + i * 16 + quad * 4;
#pragma unroll
        for (int r = 0; r < 4; ++r) {
            int row = mbase + r;
            int l = l0 + row;
            if (l < Lk) {
                float tot = rowsum[0][row] + rowsum[1][row];
                float mv = mask[b * L + l];
                float sc = mv / (sqrtf(tot) + 1e-13f);
                float* op = out + ((size_t)(b * L + l)) * OD + wn * 64 + l15;
#pragma unroll
                for (int j = 0; j < 4; ++j)
                    op[j * 16] = acc[i][j][r] * sc;
            }
        }
    }
}

// ---------------- matcher: dot tile + t-grouped geometric-chain gaussian histogram ----------------
// grid: (vtile=8, b=32, pair=9), block 256.
__global__ __launch_bounds__(256) void matcher_kernel(const float* __restrict__ qenc,
                                                      const float* __restrict__ denc,
                                                      float* __restrict__ accb) {
    __shared__ __align__(16) float lds[5440];
    float* Qs = lds;                   // [32 k][36 q]
    float* Vs = lds + 1152;            // [32 k][132 v]
    float* Sm = lds;                   // [32 q][134 v], aliased after dots (stride 67 float2)

    const int tid = threadIdx.x;
    const int pp = blockIdx.z;
    const int b = blockIdx.y;
    const int v0 = blockIdx.x * 128;
    const int qi = pp / 3;
    const int di = pp - qi * 3;
    const int Vk = 1024 - di;
    const float* qptr = qenc + qi * QENC_SZ + (size_t)b * (QL * OD);
    const float* vptr = denc + di * DENC_SZ + (size_t)b * (DL * OD);

    const int vg32 = tid & 31;
    const int qg = tid >> 5;
    const int vt = vg32 * 4;
    const int qt = qg * 4;
    float acc[4][4];
#pragma unroll
    for (int i = 0; i < 4; ++i)
#pragma unroll
        for (int j = 0; j < 4; ++j) acc[i][j] = 0.f;

    const int ks = tid & 31;
    const int rb = tid >> 5;           // 0..7

    for (int ch = 0; ch < 4; ++ch) {
        const int k0 = ch * 32;
#pragma unroll
        for (int pass = 0; pass < 4; ++pass) {
            int q = rb + pass * 8;
            Qs[ks * 36 + q] = qptr[q * OD + k0 + ks];
        }
#pragma unroll
        for (int pass = 0; pass < 16; ++pass) {
            int v = rb + pass * 8;
            Vs[ks * 132 + v] = vptr[(size_t)(v0 + v) * OD + k0 + ks];
        }
        __syncthreads();
#pragma unroll 8
        for (int k = 0; k < 32; ++k) {
            float4 qv = *reinterpret_cast<const float4*>(&Qs[k * 36 + qt]);
            float4 vv = *reinterpret_cast<const float4*>(&Vs[k * 132 + vt]);
            float qa[4] = {qv.x, qv.y, qv.z, qv.w};
            float va[4] = {vv.x, vv.y, vv.z, vv.w};
#pragma unroll
            for (int i = 0; i < 4; ++i)
#pragma unroll
                for (int j = 0; j < 4; ++j) acc[i][j] += qa[i] * va[j];
        }
        __syncthreads();
    }
    // store S tile (stride 134 floats); poison out-of-range v with 1e4 -> all kernels exactly 0
    const int vmax = min(128, Vk - v0);
#pragma unroll
    for (int i = 0; i < 4; ++i) {
        int q = qt + i;
        float2 a, c;
        a.x = (vt + 0 < vmax) ? acc[i][0] : 1.0e4f;
        a.y = (vt + 1 < vmax) ? acc[i][1] : 1.0e4f;
        c.x = (vt + 2 < vmax) ? acc[i][2] : 1.0e4f;
        c.y = (vt + 3 < vmax) ? acc[i][3] : 1.0e4f;
        *reinterpret_cast<float2*>(&Sm[q * 134 + vt]) = a;
        *reinterpret_cast<float2*>(&Sm[q * 134 + vt + 2]) = c;
    }
    __syncthreads();

    // gaussian phase: thread = (q, t-group). Groups 0-4: kernels t=1+4g..4+4g via geometric chain.
    // Group 5: the sigma=0.001 kernel (t=0). Threads 192..255 idle here.
    const int g = tid >> 5;
    const int q = tid & 31;
    if (g < 6) {
        const float* srow = &Sm[q * 134];
        float k0a = 0.f, k1a = 0.f, k2a = 0.f, k3a = 0.f;
        if (g < 5) {
            const float muf = 0.95f - 0.4f * (float)g;
#pragma unroll 8
            for (int j = 0; j < 64; ++j) {
                float2 s2 = *reinterpret_cast<const float2*>(&srow[2 * j]);
#pragma unroll
                for (int e = 0; e < 2; ++e) {
                    float s = e ? s2.y : s2.x;
                    float d = s - muf;
                    float ee = __builtin_exp2f(-72.13475204f * d * d);
                    float rr = __builtin_exp2f(fmaf(-14.426950408f, d, -0.7213475204f));
                    k0a += ee; ee *= rr; rr *= 0.36787944117f;
                    k1a += ee; ee *= rr; rr *= 0.36787944117f;
                    k2a += ee; ee *= rr;
                    k3a += ee;
                }
            }
            float* dst = &accb[((pp * NB + b) * QL + q) * KNUM + 1 + 4 * g];
            atomicAdd(&dst[0], k0a);
            atomicAdd(&dst[1], k1a);
            atomicAdd(&dst[2], k2a);
            atomicAdd(&dst[3], k3a);
        } else {
#pragma unroll 8
            for (int j = 0; j < 64; ++j) {
                float2 s2 = *reinterpret_cast<const float2*>(&srow[2 * j]);
                float d0 = s2.x - 1.0f;
                float d1 = s2.y - 1.0f;
                k0a += __builtin_exp2f(-721347.52f * d0 * d0);
                k0a += __builtin_exp2f(-721347.52f * d1 * d1);
            }
            atomicAdd(&accb[((pp * NB + b) * QL + q) * KNUM], k0a);
        }
    }
}

// ---------------- finalize ----------------
__global__ void finalize_kernel(const float* __restrict__ accb,
                                const float* __restrict__ qmask,
                                const float* __restrict__ dw,
                                const float* __restrict__ db,
                                float* __restrict__ out) {
    __shared__ float prod[192];
    int b = blockIdx.x;
    int tid = threadIdx.x;
    if (tid < 189) {
        int pq = tid / 21;
        int t = tid - pq * 21;
        int qi = pq / 3;
        int Qk = 32 - qi;
        const float* ab = accb + ((pq * NB + b) * QL) * KNUM + t;
        float s = 0.f;
        for (int q = 0; q < Qk; ++q)
            s += logf(fmaxf(ab[q * KNUM], 1e-10f)) * qmask[b * QL + q];
        float lg = s * 0.01f;
        out[NB + b * 189 + tid] = lg;
        prod[tid] = lg * dw[tid];
    }
    __syncthreads();
    if (tid == 0) {
        float sc = db[0];
        for (int i = 0; i < 189; ++i) sc += prod[i];
        out[b] = sc;
    }
}

// ---------------- launcher ----------------
extern "C" void kernel_launch(void* const* d_in, const int* in_sizes, int n_in,
                              void* d_out, int out_size, void* d_ws, size_t ws_size,
                              hipStream_t stream) {
    const int* qids = (const int*)d_in[0];
    const float* qmask = (const float*)d_in[1];
    const int* dids = (const int*)d_in[2];
    const float* dmask = (const float*)d_in[3];
    const float* emb = (const float*)d_in[4];
    const float* w1 = (const float*)d_in[5];
    const float* b1 = (const float*)d_in[6];
    const float* w2 = (const float*)d_in[7];
    const float* b2 = (const float*)d_in[8];
    const float* w3 = (const float*)d_in[9];
    const float* b3 = (const float*)d_in[10];
    const float* dw = (const float*)d_in[11];
    const float* db = (const float*)d_in[12];
    float* out = (float*)d_out;
    float* ws = (float*)d_ws;

    ushort* wp = (ushort*)(ws + WP_OFF);
    ushort* dpk = (ushort*)(ws + DPK_OFF);
    ushort* qpk = (ushort*)(ws + QPK_OFF);
    float* qenc = ws + QENC_OFF;
    float* denc = ws + DENC_OFF;
    float* accb = ws + ACC_OFF;

    hipMemsetAsync(accb, 0, ACC_SZ * sizeof(float), stream);
    prep_w_kernel<<<960, 256, 0, stream>>>(w1, w2, w3, wp);
    gather_pack<<<((NB * DL + NB * QL) * 40 + 255) / 256, 256, 0, stream>>>(emb, dids, qids, dpk, qpk);

    conv_mfma<<<dim3(9, NB, 3), 256, 0, stream>>>(dpk, qpk, dmask, qmask, wp, b1, b2, b3, denc, qenc);

    matcher_kernel<<<dim3(8, NB, 9), 256, 0, stream>>>(qenc, denc, accb);
    finalize_kernel<<<NB, 256, 0, stream>>>(accb, qmask, dw, db, out);
}

// Round 7
// 317.631 us; speedup vs baseline: 1.1582x; 1.0978x over previous
//
#include <hip/hip_runtime.h>
#include <hip/hip_bf16.h>
#include <math.h>

// ---------------- problem constants ----------------
#define NB 32
#define QL 32
#define DL 1024
#define EMB 300
#define EMBP 320            // padded K-dim per tap (zeros 300..319)
#define OD 128
#define KNUM 21
#define VOCAB 50000

typedef short short8 __attribute__((ext_vector_type(8)));
typedef float floatx4 __attribute__((ext_vector_type(4)));

// workspace layout (in float units)
static const size_t WP_OFF = 0;                        // packed bf16 weights (122880 f)
static const size_t DPK_OFF = 122880;                  // packed doc bf16 [32*1024][320]
static const size_t QPK_OFF = 5365760;                 // packed query bf16 [32*32][320]
static const size_t QENC_OFF = 8122880;
static const size_t QENC_SZ = NB * QL * OD;            // 131072
static const size_t DENC_OFF = QENC_OFF + 3 * QENC_SZ;
static const size_t DENC_SZ = (size_t)NB * DL * OD;    // 4194304
static const size_t ACC_OFF = DENC_OFF + 3 * DENC_SZ;
static const int ACC_SZ = 9 * NB * QL * KNUM;          // 193536

__device__ __constant__ int WPOFF_C[3] = {0, 40960, 122880};

// ---------------- weights -> bf16, layout [o][j*320+c] ----------------
__global__ void prep_w_kernel(const float* __restrict__ w1,
                              const float* __restrict__ w2,
                              const float* __restrict__ w3,
                              ushort* __restrict__ wp) {
    int idx = blockIdx.x * 256 + threadIdx.x;
    if (idx >= 245760) return;
    const float* src;
    int k, rel, base;
    if (idx < 40960)        { k = 1; rel = idx;          src = w1; base = 0; }
    else if (idx < 122880)  { k = 2; rel = idx - 40960;  src = w2; base = 40960; }
    else                    { k = 3; rel = idx - 122880; src = w3; base = 122880; }
    int kd = 320 * k;
    int o = rel / kd;
    int jc = rel - o * kd;
    int j = jc / EMBP;
    int c = jc - j * EMBP;
    float f = (c < EMB) ? src[(o * EMB + c) * k + j] : 0.f;
    __hip_bfloat16 h = __float2bfloat16(f);
    wp[base + rel] = *reinterpret_cast<ushort*>(&h);
}

// ---------------- gather token rows: fp32 emb -> packed bf16 [row][320] (doc + query) ----------------
__global__ void gather_pack(const float* __restrict__ emb,
                            const int* __restrict__ dids, const int* __restrict__ qids,
                            ushort* __restrict__ dpk, ushort* __restrict__ qpk) {
    int idx = blockIdx.x * 256 + threadIdx.x;    // one uint4 (8 bf16) per thread
    const int DROWS = NB * DL;
    if (idx >= (DROWS + NB * QL) * 40) return;
    int r = idx / 40;
    int c0 = (idx - r * 40) * 8;
    int rid;
    ushort* dst;
    if (r < DROWS) { rid = dids[r]; dst = dpk + (size_t)r * EMBP; }
    else           { rid = qids[r - DROWS]; dst = qpk + (size_t)(r - DROWS) * EMBP; }
    const float* erow = emb + (size_t)rid * EMB;
    ushort v[8];
    if (c0 + 8 <= EMB) {
        float4 f0 = *reinterpret_cast<const float4*>(erow + c0);
        float4 f1 = *reinterpret_cast<const float4*>(erow + c0 + 4);
        float fv[8] = {f0.x, f0.y, f0.z, f0.w, f1.x, f1.y, f1.z, f1.w};
#pragma unroll
        for (int i = 0; i < 8; ++i) {
            __hip_bfloat16 h = __float2bfloat16(fv[i]);
            v[i] = *reinterpret_cast<ushort*>(&h);
        }
    } else {
#pragma unroll
        for (int i = 0; i < 8; ++i) {
            int c = c0 + i;
            float f = (c < EMB) ? erow[c] : 0.f;
            __hip_bfloat16 h = __float2bfloat16(f);
            v[i] = *reinterpret_cast<ushort*>(&h);
        }
    }
    *reinterpret_cast<uint4*>(dst + c0) = *reinterpret_cast<uint4*>(v);
}

// ---------------- conv via bf16 MFMA, register ping-pong prefetch, doc+query in one grid ----------------
__global__ __launch_bounds__(256) void conv_mfma(const ushort* __restrict__ dpk,
                                                 const ushort* __restrict__ qpk,
                                                 const float* __restrict__ dmask,
                                                 const float* __restrict__ qmask,
                                                 const ushort* __restrict__ wp,
                                                 const float* __restrict__ b1,
                                                 const float* __restrict__ b2,
                                                 const float* __restrict__ b3,
                                                 float* __restrict__ denc,
                                                 float* __restrict__ qenc) {
    __shared__ float rowsum[2][128];

    const int tid = threadIdx.x;
    const int b = blockIdx.y;
    const int z = blockIdx.z;
    const bool isq = (blockIdx.x == 8);
    const ushort* xs = isq ? qpk : dpk;
    const float* mask = isq ? qmask : dmask;
    const int L = isq ? QL : DL;
    const size_t enc_sz = isq ? QENC_SZ : DENC_SZ;
    const int l0 = isq ? 0 : blockIdx.x * 128;
    const int Kdim = EMBP * (z + 1);
    const int NH = 10 * (z + 1);
    const int Lk = L - z;
    const ushort* wpk = wp + WPOFF_C[z];
    const ushort* xb = xs + (size_t)b * L * EMBP;
    const float* bias = (z == 0) ? b1 : ((z == 1) ? b2 : b3);
    float* out = (isq ? qenc : denc) + (size_t)z * enc_sz;

    const int wave = tid >> 6;
    const int lane = tid & 63;
    const int wm = wave >> 1;
    const int wn = wave & 1;
    const int l15 = lane & 15;
    const int quad = lane >> 4;

    floatx4 acc[4][4];
#pragma unroll
    for (int i = 0; i < 4; ++i)
#pragma unroll
        for (int j = 0; j < 4; ++j) acc[i][j] = (floatx4)0.f;

    auto load_frags = [&](int hh, short8* A, short8* B) {
        int ch = hh >> 1;
        int h = hh & 1;
        int jj = ch / 5;
        int c0 = (ch - jj * 5) << 6;
        int aoff = c0 + h * 32 + (quad << 3);
        int boff = (ch << 6) + h * 32 + (quad << 3);
#pragma unroll
        for (int i = 0; i < 4; ++i) {
            int row = l0 + wm * 64 + i * 16 + l15 + jj;
            if (row > L - 1) row = L - 1;
            A[i] = *reinterpret_cast<const short8*>(xb + (size_t)row * EMBP + aoff);
            int n = wn * 64 + i * 16 + l15;
            B[i] = *reinterpret_cast<const short8*>(wpk + (size_t)n * Kdim + boff);
        }
    };

    short8 afA[4], bfA[4], afB[4], bfB[4];
    load_frags(0, afA, bfA);
    for (int hh = 0; hh < NH; hh += 2) {
        load_frags(hh + 1, afB, bfB);
#pragma unroll
        for (int i = 0; i < 4; ++i)
#pragma unroll
            for (int j = 0; j < 4; ++j)
                acc[i][j] = __builtin_amdgcn_mfma_f32_16x16x32_bf16(afA[i], bfA[j], acc[i][j], 0, 0, 0);
        int nx = (hh + 2 < NH) ? hh + 2 : NH - 1;
        load_frags(nx, afA, bfA);
#pragma unroll
        for (int i = 0; i < 4; ++i)
#pragma unroll
            for (int j = 0; j < 4; ++j)
                acc[i][j] = __builtin_amdgcn_mfma_f32_16x16x32_bf16(afB[i], bfB[j], acc[i][j], 0, 0, 0);
    }

    float bv[4];
#pragma unroll
    for (int j = 0; j < 4; ++j) bv[j] = bias[wn * 64 + j * 16 + l15];
#pragma unroll
    for (int i = 0; i < 4; ++i)
#pragma unroll
        for (int r = 0; r < 4; ++r) {
            float p = 0.f;
#pragma unroll
            for (int j = 0; j < 4; ++j) {
                float y = fmaxf(acc[i][j][r] + bv[j], 0.f);
                acc[i][j][r] = y;
                p += y * y;
            }
#pragma unroll
            for (int m = 1; m < 16; m <<= 1) p += __shfl_xor(p, m, 64);
            if (l15 == 0) rowsum[wn][wm * 64 + i * 16 + quad * 4 + r] = p;
        }
    __syncthreads();

#pragma unroll
    for (int i = 0; i < 4; ++i) {
        int mbase = wm * 64 + i * 16 + quad * 4;
#pragma unroll
        for (int r = 0; r < 4; ++r) {
            int row = mbase + r;
            int l = l0 + row;
            if (l < Lk) {
                float tot = rowsum[0][row] + rowsum[1][row];
                float mv = mask[b * L + l];
                float sc = mv / (sqrtf(tot) + 1e-13f);
                float* op = out + ((size_t)(b * L + l)) * OD + wn * 64 + l15;
#pragma unroll
                for (int j = 0; j < 4; ++j)
                    op[j * 16] = acc[i][j][r] * sc;
            }
        }
    }
}

// ---------------- matcher: split-precision MFMA dots + gaussian histogram ----------------
// grid: (vtile=8, b=32, pair=9), block 256 = 4 waves. Tile 32q x 128v, K=128 in 2 chunks of 64.
// s = hiQ*hiV + hiQ*loV + loQ*hiV  (3 chained bf16 MFMAs; error ~1e-5, preserves sigma=0.001 kernel)
__global__ __launch_bounds__(256) void matcher_kernel(const float* __restrict__ qenc,
                                                      const float* __restrict__ denc,
                                                      float* __restrict__ accb) {
    __shared__ __align__(16) ushort ldsbuf[23040];   // 46 KB; S (32x130 f32) aliases after dots
    const int QH = 0, QLo = 2304, VH = 4608, VLo = 13824;

    const int tid = threadIdx.x;
    const int pp = blockIdx.z;
    const int b = blockIdx.y;
    const int v0 = blockIdx.x * 128;
    const int qi = pp / 3;
    const int di = pp - qi * 3;
    const int Vk = 1024 - di;
    const float* qptr = qenc + qi * QENC_SZ + (size_t)b * (QL * OD);
    const float* vptr = denc + di * DENC_SZ + (size_t)b * (DL * OD);

    const int wave = tid >> 6;
    const int lane = tid & 63;
    const int l15 = lane & 15;
    const int quad = lane >> 4;

    floatx4 acc[2][2];
#pragma unroll
    for (int i = 0; i < 2; ++i)
#pragma unroll
        for (int j = 0; j < 2; ++j) acc[i][j] = (floatx4)0.f;

    // staging maps
    const int qrow = tid >> 3, qseg = (tid & 7) * 8;        // Q: 32 rows x 8 segs
    const int vrow = tid >> 1, vseg = (tid & 1) * 32;       // V: 128 rows x 2 segs

    for (int ch = 0; ch < 2; ++ch) {
        const int k0 = ch * 64;
        // ---- stage Q (hi/lo split) ----
        {
            const float* src = qptr + qrow * OD + k0 + qseg;
            float4 f0 = *reinterpret_cast<const float4*>(src);
            float4 f1 = *reinterpret_cast<const float4*>(src + 4);
            float fv[8] = {f0.x, f0.y, f0.z, f0.w, f1.x, f1.y, f1.z, f1.w};
            ushort hi8[8], lo8[8];
#pragma unroll
            for (int i = 0; i < 8; ++i) {
                __hip_bfloat16 h = __float2bfloat16(fv[i]);
                float hf = __bfloat162float(h);
                __hip_bfloat16 l = __float2bfloat16(fv[i] - hf);
                hi8[i] = *reinterpret_cast<ushort*>(&h);
                lo8[i] = *reinterpret_cast<ushort*>(&l);
            }
            *reinterpret_cast<uint4*>(&ldsbuf[QH + qrow * 72 + qseg]) = *reinterpret_cast<uint4*>(hi8);
            *reinterpret_cast<uint4*>(&ldsbuf[QLo + qrow * 72 + qseg]) = *reinterpret_cast<uint4*>(lo8);
        }
        // ---- stage V (hi/lo split) ----
        {
            const float* src = vptr + (size_t)(v0 + vrow) * OD + k0 + vseg;
#pragma unroll
            for (int g = 0; g < 4; ++g) {
                float4 f0 = *reinterpret_cast<const float4*>(src + g * 8);
                float4 f1 = *reinterpret_cast<const float4*>(src + g * 8 + 4);
                float fv[8] = {f0.x, f0.y, f0.z, f0.w, f1.x, f1.y, f1.z, f1.w};
                ushort hi8[8], lo8[8];
#pragma unroll
                for (int i = 0; i < 8; ++i) {
                    __hip_bfloat16 h = __float2bfloat16(fv[i]);
                    float hf = __bfloat162float(h);
                    __hip_bfloat16 l = __float2bfloat16(fv[i] - hf);
                    hi8[i] = *reinterpret_cast<ushort*>(&h);
                    lo8[i] = *reinterpret_cast<ushort*>(&l);
                }
                *reinterpret_cast<uint4*>(&ldsbuf[VH + vrow * 72 + vseg + g * 8]) = *reinterpret_cast<uint4*>(hi8);
                *reinterpret_cast<uint4*>(&ldsbuf[VLo + vrow * 72 + vseg + g * 8]) = *reinterpret_cast<uint4*>(lo8);
            }
        }
        __syncthreads();
        // ---- MFMA: wave owns v-range [wave*32, wave*32+32) ----
#pragma unroll
        for (int kf = 0; kf < 2; ++kf) {
            const int ko = kf * 32 + (quad << 3);
            short8 qh[2], ql[2], vh[2], vl[2];
#pragma unroll
            for (int i = 0; i < 2; ++i) {
                qh[i] = *reinterpret_cast<const short8*>(&ldsbuf[QH + (i * 16 + l15) * 72 + ko]);
                ql[i] = *reinterpret_cast<const short8*>(&ldsbuf[QLo + (i * 16 + l15) * 72 + ko]);
                int n = wave * 32 + i * 16 + l15;
                vh[i] = *reinterpret_cast<const short8*>(&ldsbuf[VH + n * 72 + ko]);
                vl[i] = *reinterpret_cast<const short8*>(&ldsbuf[VLo + n * 72 + ko]);
            }
#pragma unroll
            for (int i = 0; i < 2; ++i)
#pragma unroll
                for (int j = 0; j < 2; ++j) {
                    acc[i][j] = __builtin_amdgcn_mfma_f32_16x16x32_bf16(qh[i], vh[j], acc[i][j], 0, 0, 0);
                    acc[i][j] = __builtin_amdgcn_mfma_f32_16x16x32_bf16(qh[i], vl[j], acc[i][j], 0, 0, 0);
                    acc[i][j] = __builtin_amdgcn_mfma_f32_16x16x32_bf16(ql[i], vh[j], acc[i][j], 0, 0, 0);
                }
        }
        __syncthreads();
    }

    // ---- S tile to LDS (stride 130 f32), poison v >= vmax with 1e4 ----
    float* Sm = reinterpret_cast<float*>(ldsbuf);
    const int vmax = min(128, Vk - v0);
#pragma unroll
    for (int i = 0; i < 2; ++i)
#pragma unroll
        for (int j = 0; j < 2; ++j)
#pragma unroll
            for (int r = 0; r < 4; ++r) {
                int q = i * 16 + quad * 4 + r;
                int v = wave * 32 + j * 16 + l15;
                float val = acc[i][j][r];
                if (v >= vmax) val = 1.0e4f;
                Sm[q * 130 + v] = val;
            }
    __syncthreads();

    // ---- gaussian phase: thread = (q, t), one accumulator, float2 reads (2-way free) ----
    for (int idx = tid; idx < 32 * KNUM; idx += 256) {
        int q = idx & 31;
        int t = idx >> 5;
        float mu = (t == 0) ? 1.0f : 0.95f - 0.1f * (float)(t - 1);
        float Am = (t == 0) ? -721347.52f : -72.13475204f;   // -log2e/(2 sigma^2)
        const float* srow = &Sm[q * 130];
        float a = 0.f;
#pragma unroll 8
        for (int j = 0; j < 64; ++j) {
            float2 s2 = *reinterpret_cast<const float2*>(&srow[2 * j]);
            float d0 = s2.x - mu;
            float d1 = s2.y - mu;
            a += __builtin_exp2f(Am * d0 * d0);
            a += __builtin_exp2f(Am * d1 * d1);
        }
        atomicAdd(&accb[((pp * NB + b) * QL + q) * KNUM + t], a);
    }
}

// ---------------- finalize ----------------
__global__ void finalize_kernel(const float* __restrict__ accb,
                                const float* __restrict__ qmask,
                                const float* __restrict__ dw,
                                const float* __restrict__ db,
                                float* __restrict__ out) {
    __shared__ float prod[192];
    int b = blockIdx.x;
    int tid = threadIdx.x;
    if (tid < 189) {
        int pq = tid / 21;
        int t = tid - pq * 21;
        int qi = pq / 3;
        int Qk = 32 - qi;
        const float* ab = accb + ((pq * NB + b) * QL) * KNUM + t;
        float s = 0.f;
        for (int q = 0; q < Qk; ++q)
            s += logf(fmaxf(ab[q * KNUM], 1e-10f)) * qmask[b * QL + q];
        float lg = s * 0.01f;
        out[NB + b * 189 + tid] = lg;
        prod[tid] = lg * dw[tid];
    }
    __syncthreads();
    if (tid == 0) {
        float sc = db[0];
        for (int i = 0; i < 189; ++i) sc += prod[i];
        out[b] = sc;
    }
}

// ---------------- launcher ----------------
extern "C" void kernel_launch(void* const* d_in, const int* in_sizes, int n_in,
                              void* d_out, int out_size, void* d_ws, size_t ws_size,
                              hipStream_t stream) {
    const int* qids = (const int*)d_in[0];
    const float* qmask = (const float*)d_in[1];
    const int* dids = (const int*)d_in[2];
    const float* dmask = (const float*)d_in[3];
    const float* emb = (const float*)d_in[4];
    const float* w1 = (const float*)d_in[5];
    const float* b1 = (const float*)d_in[6];
    const float* w2 = (const float*)d_in[7];
    const float* b2 = (const float*)d_in[8];
    const float* w3 = (const float*)d_in[9];
    const float* b3 = (const float*)d_in[10];
    const float* dw = (const float*)d_in[11];
    const float* db = (const float*)d_in[12];
    float* out = (float*)d_out;
    float* ws = (float*)d_ws;

    ushort* wp = (ushort*)(ws + WP_OFF);
    ushort* dpk = (ushort*)(ws + DPK_OFF);
    ushort* qpk = (ushort*)(ws + QPK_OFF);
    float* qenc = ws + QENC_OFF;
    float* denc = ws + DENC_OFF;
    float* accb = ws + ACC_OFF;

    hipMemsetAsync(accb, 0, ACC_SZ * sizeof(float), stream);
    prep_w_kernel<<<960, 256, 0, stream>>>(w1, w2, w3, wp);
    gather_pack<<<((NB * DL + NB * QL) * 40 + 255) / 256, 256, 0, stream>>>(emb, dids, qids, dpk, qpk);

    conv_mfma<<<dim3(9, NB, 3), 256, 0, stream>>>(dpk, qpk, dmask, qmask, wp, b1, b2, b3, denc, qenc);

    matcher_kernel<<<dim3(8, NB, 9), 256, 0, stream>>>(qenc, denc, accb);
    finalize_kernel<<<NB, 256, 0, stream>>>(accb, qmask, dw, db, out);
}